// Round 8
// baseline (137.448 us; speedup 1.0000x reference)
//
#include <hip/hip_runtime.h>

typedef __attribute__((ext_vector_type(4))) float f32x4;
typedef __attribute__((ext_vector_type(16))) float f32x16;
typedef __attribute__((ext_vector_type(8))) short bf16x8;

#define DEVFN static __device__ __forceinline__

DEVFN unsigned short f2bf(float f) {
  union { float f; unsigned u; } x; x.f = f;
  unsigned r = x.u + 0x7fffu + ((x.u >> 16) & 1u);
  return (unsigned short)(r >> 16);
}
DEVFN float bf2f(unsigned short u) {
  union { unsigned u; float f; } x; x.u = ((unsigned)u) << 16;
  return x.f;
}

DEVFN void gload_lds16(const unsigned short* g, unsigned short* l) {
  __builtin_amdgcn_global_load_lds(
      (const __attribute__((address_space(1))) unsigned int*)g,
      (__attribute__((address_space(3))) unsigned int*)l, 16, 0, 0);
}

// ---------------------------------------------------------------------------
// prep kernel: fused {fp32->bf16 casts} + {z-weight transpose-cast} + {F bias}
// Grid layout: [0, castChunks) cast ; [castChunks, +192) tcast ; [+192,+132) F.
// ---------------------------------------------------------------------------
#define NSEG 8
struct SegTable {
  const float* src[NSEG];
  unsigned short* dst[NSEG];
  int chunks[NSEG];
};

__global__ __launch_bounds__(256) void prep_kernel(
    SegTable st, int castChunks,
    const float* __restrict__ zh_w, const float* __restrict__ zx_w,
    const float* __restrict__ zb_w, unsigned short* __restrict__ WzT,
    const float* __restrict__ zh_b, const float* __restrict__ zx_b,
    const float* __restrict__ db_b, const float* __restrict__ dh_w,
    const float* __restrict__ dx_w, float* __restrict__ F) {
  __shared__ float T[64][65];
  const int tid = threadIdx.x;
  int b = blockIdx.x;

  if (b < castChunks) {  // ---- segment casts ----
    int c = b, s = 0;
    while (c >= st.chunks[s]) { c -= st.chunks[s]; ++s; }
    const float* src = st.src[s] + (long)c * 4096;
    unsigned short* dst = st.dst[s] + (long)c * 4096;
#pragma unroll
    for (int i = 0; i < 4; ++i) {
      float4 v = *(const float4*)(src + tid * 4 + i * 1024);
      ushort4 o;
      o.x = f2bf(v.x); o.y = f2bf(v.y); o.z = f2bf(v.z); o.w = f2bf(v.w);
      *(ushort4*)(dst + tid * 4 + i * 1024) = o;
    }
    return;
  }
  b -= castChunks;

  if (b < 192) {  // ---- tcast_z: WzT[zz][k][j] = zw_t[g*256+j][k] ----
    const int zz = b >> 4, rem = b & 15;
    const int t = zz >> 2, g = zz & 3;
    const float* src =
        (t == 0 ? zh_w : (t == 1 ? zx_w : zb_w)) + (long)g * 65536;
    unsigned short* dst = WzT + (long)zz * 65536;
    const int j0 = (rem & 3) * 64, k0 = (rem >> 2) * 64;
    const int jr = tid >> 2, kc = (tid & 3) * 16;
#pragma unroll
    for (int i = 0; i < 4; ++i) {
      float4 v = *(const float4*)(src + (long)(j0 + jr) * 256 + k0 + kc + i * 4);
      T[jr][kc + i * 4 + 0] = v.x;
      T[jr][kc + i * 4 + 1] = v.y;
      T[jr][kc + i * 4 + 2] = v.z;
      T[jr][kc + i * 4 + 3] = v.w;
    }
    __syncthreads();
    const int kr = tid >> 2, jc = (tid & 3) * 16;
    unsigned short tmp[16];
#pragma unroll
    for (int i = 0; i < 16; ++i) tmp[i] = f2bf(T[jc + i][kr]);
    *(bf16x8*)(dst + (long)(k0 + kr) * 256 + j0 + jc) = *(bf16x8*)&tmp[0];
    *(bf16x8*)(dst + (long)(k0 + kr) * 256 + j0 + jc + 8) = *(bf16x8*)&tmp[8];
    return;
  }
  b -= 192;

  // ---- fbias: F[0/1][g][h] = sum_j zb[t][g*256+j]*dw_t[g][h][j]; F[2]=db_b
  if (b >= 128) {
    const int idx = (b - 128) * 1024 + tid * 4;
    *(float4*)(F + 8192 + idx) = *(const float4*)(db_b + idx);
    return;
  }
  const int wgid = b * 4 + (tid >> 6);  // 0..511
  const int lane = tid & 63;
  const int t = wgid >> 8, g = (wgid >> 6) & 3, hbase = (wgid & 63) * 16;
  const float* zb = (t == 0 ? zh_b : zx_b) + g * 256;
  const float* dw = (t == 0 ? dh_w : dx_w) + (long)g * 262144;
  float4 zv = *(const float4*)(zb + lane * 4);
#pragma unroll
  for (int i = 0; i < 16; ++i) {
    const int h = hbase + i;
    float4 wv = *(const float4*)(dw + (long)h * 256 + lane * 4);
    float s = zv.x * wv.x + zv.y * wv.y + zv.z * wv.z + zv.w * wv.w;
#pragma unroll
    for (int off = 32; off; off >>= 1) s += __shfl_down(s, off);
    if (lane == 0) F[(t * 4 + g) * 1024 + h] = s;
  }
}

// ---------------------------------------------------------------------------
// 128x128 NT bf16 GEMM body (m97 structure) with bank-remapped LDS:
// 16B slot L holds global (row, sig): L = (row>>3)*32 + 8*sig + (row&7)
// => ds_read bank-group = (row&7)*4 (uniform minimum for the frag reads).
// ---------------------------------------------------------------------------
DEVFN void gemm128_body(const unsigned short* __restrict__ A,
                        const unsigned short* __restrict__ W,
                        unsigned short* __restrict__ C,
                        const float* __restrict__ bias,
                        int lda, int ldb, int ldc, int K,
                        int bx, int by,
                        unsigned short* As, unsigned short* Bs) {
  const int m0 = by * 128, n0 = bx * 128;
  const int tid = threadIdx.x;
  const int lane = tid & 63, wid = tid >> 6;
  const int wr = wid >> 1, wc = wid & 1;

  // staging: L = tid covers (row = (tid>>5)*8 + (tid&7), sig = (tid>>3)&3)
  const int srow = (tid >> 5) * 8 + (tid & 7);
  const int scol = ((tid >> 3) & 3) * 8;
  const unsigned short* Ag0 = A + (long)(m0 + srow) * lda + scol;
  const unsigned short* Ag1 = A + (long)(m0 + 64 + srow) * lda + scol;
  const unsigned short* Wg0 = W + (long)(n0 + srow) * ldb + scol;
  const unsigned short* Wg1 = W + (long)(n0 + 64 + srow) * ldb + scol;
  unsigned short* As0 = &As[tid * 8];
  unsigned short* As1 = &As[2048 + tid * 8];
  unsigned short* Bs0 = &Bs[tid * 8];
  unsigned short* Bs1 = &Bs[2048 + tid * 8];

  const int r = lane & 15, q = lane >> 4;

  f32x4 acc[4][4];
#pragma unroll
  for (int m = 0; m < 4; ++m)
#pragma unroll
    for (int n = 0; n < 4; ++n) acc[m][n] = (f32x4)0.f;

  for (int k0 = 0; k0 < K; k0 += 32) {
    gload_lds16(Ag0 + k0, As0);
    gload_lds16(Ag1 + k0, As1);
    gload_lds16(Wg0 + k0, Bs0);
    gload_lds16(Wg1 + k0, Bs1);
    __syncthreads();

    bf16x8 af[4], bfr[4];
#pragma unroll
    for (int m = 0; m < 4; ++m)
      af[m] = *(const bf16x8*)&As[(wr * 8 + m * 2 + (r >> 3)) * 256 +
                                  (r & 7) * 8 + q * 64];
#pragma unroll
    for (int n = 0; n < 4; ++n)
      bfr[n] = *(const bf16x8*)&Bs[(wc * 8 + n * 2 + (r >> 3)) * 256 +
                                   (r & 7) * 8 + q * 64];
#pragma unroll
    for (int m = 0; m < 4; ++m)
#pragma unroll
      for (int n = 0; n < 4; ++n)
        acc[m][n] = __builtin_amdgcn_mfma_f32_16x16x32_bf16(af[m], bfr[n],
                                                            acc[m][n], 0, 0, 0);
    __syncthreads();
  }

#pragma unroll
  for (int m = 0; m < 4; ++m) {
    const int row = m0 + wr * 64 + m * 16 + (lane >> 4) * 4;
#pragma unroll
    for (int n = 0; n < 4; ++n) {
      const int col = n0 + wc * 64 + n * 16 + r;
      float bv = bias ? bias[col] : 0.f;
#pragma unroll
      for (int j = 0; j < 4; ++j) {
        float v = acc[m][n][j] + bv;
        C[(long)(row + j) * ldc + col] = f2bf(v);
      }
    }
  }
}

// E-GEMM: E[zz] (1024h x 256k) = Wd[zz] @ WzT[zz] (NT)
__global__ __launch_bounds__(256) void gemm_e(
    const unsigned short* __restrict__ Wd, const unsigned short* __restrict__ WzT,
    unsigned short* __restrict__ E) {
  __shared__ __align__(16) unsigned short As[4096];
  __shared__ __align__(16) unsigned short Bs[4096];
  const int zz = blockIdx.z;
  gemm128_body(Wd + (long)zz * 262144, WzT + (long)zz * 65536,
               E + (long)zz * 262144, nullptr,
               256, 256, 256, 256, blockIdx.x, blockIdx.y, As, Bs);
}

// d-GEMMs: dall[t][:, g*1024..] = meta @ E[zz]^T-form + F[zz]
__global__ __launch_bounds__(256) void gemm_d(
    const unsigned short* __restrict__ meta_bf, const unsigned short* __restrict__ E,
    unsigned short* __restrict__ dall, const float* __restrict__ F) {
  __shared__ __align__(16) unsigned short As[4096];
  __shared__ __align__(16) unsigned short Bs[4096];
  const int zz = blockIdx.z;
  unsigned short* C = dall + (long)(zz >> 2) * 8388608 + (zz & 3) * 1024;
  gemm128_body(meta_bf, E + (long)zz * 262144, C, F + zz * 1024,
               256, 256, 4096, 256, blockIdx.x, blockIdx.y, As, Bs);
}

// ---------------------------------------------------------------------------
// 256x256 / BK=64 / 8-wave / 32x32x16 bf16 GEMM (round-4 proven choreography)
// with bank-remapped LDS: 16B slot L holds (row, sig):
//   L = (row>>3)*64 + 8*sig + (row&7)  => bank-group = (row&7)*4.
// Staging source: row = (tid>>6)*8 + (tid&7), sig = (tid>>3)&7 (same global
// coalescing: a wave covers 8 full 128B rows).
// ---------------------------------------------------------------------------
__global__ __launch_bounds__(512, 2) void gemm256_whx(
    const unsigned short* __restrict__ Aall,   // [2][2048][1024]
    const unsigned short* __restrict__ Ball,   // [2][4096][1024]
    unsigned short* __restrict__ Call) {       // [2][2048][4096]
  __shared__ __align__(16) unsigned short As[2][2][8192];  // [buf][half][128*64]
  __shared__ __align__(16) unsigned short Bs[2][2][8192];

  const int bid = blockIdx.x;
  const int swz = (bid & 7) * 32 + (bid >> 3);
  const int z = swz >> 7;
  const int rr = swz & 127;
  const int sb = rr >> 5, wq = rr & 31;
  const int my = (sb & 1) * 4 + (wq >> 3);   // 0..7
  const int nx = (sb >> 1) * 8 + (wq & 7);   // 0..15

  const unsigned short* Ag = Aall + (long)z * 2097152 + (long)my * 262144;
  const unsigned short* Bg = Ball + (long)z * 4194304 + (long)nx * 262144;
  unsigned short* Cg = Call + (long)z * 8388608 + (long)my * 1048576 + nx * 256;

  const int tid = threadIdx.x;
  const int lane = tid & 63, wid = tid >> 6;
  const int wm = wid >> 2, wn = wid & 3;       // 2 x 4 wave grid
  const int l31 = lane & 31, l5 = lane >> 5;

  // staging geometry (bank-remap)
  const int srow = (tid >> 6) * 8 + (tid & 7);
  const int gcol = ((tid >> 3) & 7) * 8;
  const unsigned short* AgS = Ag + (long)srow * 1024 + gcol;
  const unsigned short* BgS = Bg + (long)srow * 1024 + gcol;

  auto stageA = [&](int buf, int half, int kt) {
    const unsigned short* s = AgS + half * 131072 + kt * 64;
    unsigned short* d = &As[buf][half][tid * 8];
    gload_lds16(s, d);
    gload_lds16(s + 65536, d + 4096);  // row+64, same sig -> L+512
  };
  auto stageB = [&](int buf, int half, int kt) {
    const unsigned short* s = BgS + half * 131072 + kt * 64;
    unsigned short* d = &Bs[buf][half][tid * 8];
    gload_lds16(s, d);
    gload_lds16(s + 65536, d + 4096);
  };

  // frag read offsets (elems): L*8 = (row>>3)*512 + sig*64 + (row&7)*8
  int koff[4];
#pragma unroll
  for (int ks = 0; ks < 4; ++ks) koff[ks] = (ks * 2 + l5) * 64;

  const int bhalf = wn >> 1;
  int brow[2];
#pragma unroll
  for (int nt = 0; nt < 2; ++nt)
    brow[nt] = ((wn & 1) * 8 + nt * 4 + (l31 >> 3)) * 512 + (l31 & 7) * 8;
  int arow[4];
#pragma unroll
  for (int mt = 0; mt < 4; ++mt)
    arow[mt] = (mt * 4 + (l31 >> 3)) * 512 + (l31 & 7) * 8;

  f32x16 acc[4][2];  // [mt][nt]
#pragma unroll
  for (int m = 0; m < 4; ++m)
#pragma unroll
    for (int n = 0; n < 2; ++n) acc[m][n] = (f32x16)0.f;

  stageA(0, 0, 0); stageB(0, 0, 0); stageA(0, 1, 0); stageB(0, 1, 0);
  stageA(1, 0, 1); stageB(1, 0, 1);
  asm volatile("s_waitcnt vmcnt(4)" ::: "memory");  // tile0 landed
  __builtin_amdgcn_s_barrier();

#pragma unroll 2
  for (int T = 0; T < 16; ++T) {
    const int buf = T & 1, nb = buf ^ 1;

    if (T < 15) { stageA(nb, 1, T + 1); stageB(nb, 1, T + 1); }

    bf16x8 bfg[2][4], af[2][4];
    const unsigned short* Ab = &As[buf][wm][0];
    {
      const unsigned short* Bb = &Bs[buf][bhalf][0];
#pragma unroll
      for (int nt = 0; nt < 2; ++nt)
#pragma unroll
        for (int ks = 0; ks < 4; ++ks)
          bfg[nt][ks] = *(const bf16x8*)(Bb + brow[nt] + koff[ks]);
#pragma unroll
      for (int m2 = 0; m2 < 2; ++m2)
#pragma unroll
        for (int ks = 0; ks < 4; ++ks)
          af[m2][ks] = *(const bf16x8*)(Ab + arow[m2] + koff[ks]);
    }

    __builtin_amdgcn_s_setprio(1);
#pragma unroll
    for (int m2 = 0; m2 < 2; ++m2)
#pragma unroll
      for (int nt = 0; nt < 2; ++nt)
#pragma unroll
        for (int ks = 0; ks < 4; ++ks)
          acc[m2][nt] = __builtin_amdgcn_mfma_f32_32x32x16_bf16(
              af[m2][ks], bfg[nt][ks], acc[m2][nt], 0, 0, 0);
    __builtin_amdgcn_s_setprio(0);

#pragma unroll
    for (int m2 = 0; m2 < 2; ++m2)
#pragma unroll
      for (int ks = 0; ks < 4; ++ks)
        af[m2][ks] = *(const bf16x8*)(Ab + arow[2 + m2] + koff[ks]);

    asm volatile("s_waitcnt lgkmcnt(0)" ::: "memory");
    __builtin_amdgcn_sched_barrier(0);
    __builtin_amdgcn_s_barrier();

    if (T < 14) { stageA(buf, 0, T + 2); stageB(buf, 0, T + 2); }

    __builtin_amdgcn_s_setprio(1);
#pragma unroll
    for (int m2 = 0; m2 < 2; ++m2)
#pragma unroll
      for (int nt = 0; nt < 2; ++nt)
#pragma unroll
        for (int ks = 0; ks < 4; ++ks)
          acc[2 + m2][nt] = __builtin_amdgcn_mfma_f32_32x32x16_bf16(
              af[m2][ks], bfg[nt][ks], acc[2 + m2][nt], 0, 0, 0);
    __builtin_amdgcn_s_setprio(0);

    if (T < 14) {
      asm volatile("s_waitcnt vmcnt(4)" ::: "memory");
      __builtin_amdgcn_s_barrier();
    } else if (T == 14) {
      asm volatile("s_waitcnt vmcnt(0)" ::: "memory");
      __builtin_amdgcn_s_barrier();
    }
  }

  // epilogue: 32x32 C/D layout: col = lane&31, row = (reg&3)+8*(reg>>2)+4*l5
#pragma unroll
  for (int mt = 0; mt < 4; ++mt) {
#pragma unroll
    for (int nt = 0; nt < 2; ++nt) {
      const int rb = wm * 128 + mt * 32 + 4 * l5;
      const int cb = wn * 64 + nt * 32 + l31;
#pragma unroll
      for (int reg = 0; reg < 16; ++reg) {
        const int row = rb + (reg & 3) + 8 * (reg >> 2);
        Cg[(long)row * 4096 + cb] = f2bf(acc[mt][nt][reg]);
      }
    }
  }
}

// ---------------------------------------------------------------------------
// Epilogue: y = d_h*wh + d_x*wx + d_b ; per-(b,g) LayerNorm ; LSTM gates.
// ---------------------------------------------------------------------------
DEVFN void ld4bf(const unsigned short* p, float* o) {
  ushort4 v = *(const ushort4*)p;
  o[0] = bf2f(v.x); o[1] = bf2f(v.y); o[2] = bf2f(v.z); o[3] = bf2f(v.w);
}

__global__ __launch_bounds__(256) void epilogue_kernel(
    const unsigned short* __restrict__ d_all,   // [3][2048][4096] bf16
    const unsigned short* __restrict__ whx,     // [2][2048][4096] bf16
    const float* __restrict__ c_in,             // [2048][1024]
    const float* __restrict__ ln_w, const float* __restrict__ ln_b,
    float* __restrict__ out) {
  const long b = blockIdx.x;
  const int t = threadIdx.x;
  const int lane = t & 63, wid = t >> 6;

  const unsigned short* dh = d_all + b * 4096;
  const unsigned short* dx = d_all + 8388608L + b * 4096;
  const unsigned short* db = d_all + 16777216L + b * 4096;
  const unsigned short* wh = whx + b * 4096;
  const unsigned short* wx = whx + 8388608L + b * 4096;

  __shared__ float redS[4][4], redQ[4][4];
  float y[4][4];

#pragma unroll
  for (int g = 0; g < 4; ++g) {
    const int base = g * 1024 + t * 4;
    float fdh[4], fdx[4], fdb[4], fwh[4], fwx[4];
    ld4bf(dh + base, fdh);
    ld4bf(dx + base, fdx);
    ld4bf(db + base, fdb);
    ld4bf(wh + base, fwh);
    ld4bf(wx + base, fwx);
    float s = 0.f, sq = 0.f;
#pragma unroll
    for (int j = 0; j < 4; ++j) {
      float v = fdh[j] * fwh[j] + fdx[j] * fwx[j] + fdb[j];
      y[g][j] = v;
      s += v;
      sq += v * v;
    }
#pragma unroll
    for (int off = 32; off; off >>= 1) {
      s += __shfl_down(s, off);
      sq += __shfl_down(sq, off);
    }
    if (lane == 0) { redS[g][wid] = s; redQ[g][wid] = sq; }
  }
  __syncthreads();

  float yn[4][4];
#pragma unroll
  for (int g = 0; g < 4; ++g) {
    float S = redS[g][0] + redS[g][1] + redS[g][2] + redS[g][3];
    float SQ = redQ[g][0] + redQ[g][1] + redQ[g][2] + redQ[g][3];
    float mu = S * (1.f / 1024.f);
    float var = SQ * (1.f / 1024.f) - mu * mu;
    float rs = rsqrtf(var + 1e-5f);
    const int base = g * 1024 + t * 4;
    float4 lw = *(const float4*)(ln_w + base);
    float4 lb = *(const float4*)(ln_b + base);
    yn[g][0] = (y[g][0] - mu) * rs * lw.x + lb.x;
    yn[g][1] = (y[g][1] - mu) * rs * lw.y + lb.y;
    yn[g][2] = (y[g][2] - mu) * rs * lw.z + lb.z;
    yn[g][3] = (y[g][3] - mu) * rs * lw.w + lb.w;
  }

  float4 cp = *(const float4*)(c_in + b * 1024 + t * 4);
  float cin[4] = {cp.x, cp.y, cp.z, cp.w};
  float hn[4], cn[4];
#pragma unroll
  for (int j = 0; j < 4; ++j) {
    float ii = yn[0][j], ff = yn[1][j], gg = yn[2][j], oo = yn[3][j];
    float si = 1.f / (1.f + expf(-ii));
    float sf = 1.f / (1.f + expf(-ff));
    float so = 1.f / (1.f + expf(-oo));
    float cnj = sf * cin[j] + si * tanhf(gg);
    cn[j] = cnj;
    hn[j] = so * tanhf(cnj);
  }
  float4 ho = {hn[0], hn[1], hn[2], hn[3]};
  float4 co = {cn[0], cn[1], cn[2], cn[3]};
  *(float4*)(out + b * 1024 + t * 4) = ho;
  *(float4*)(out + 2097152L + b * 1024 + t * 4) = co;
}

// ---------------------------------------------------------------------------
extern "C" void kernel_launch(void* const* d_in, const int* in_sizes, int n_in,
                              void* d_out, int out_size, void* d_ws,
                              size_t ws_size, hipStream_t stream) {
  const float* src_x = (const float*)d_in[0];
  const float* h_in  = (const float*)d_in[1];
  const float* c_in  = (const float*)d_in[2];
  const float* meta  = (const float*)d_in[3];
  const float* zh_w  = (const float*)d_in[4];
  const float* zh_b  = (const float*)d_in[5];
  const float* zx_w  = (const float*)d_in[6];
  const float* zx_b  = (const float*)d_in[7];
  const float* zb_w  = (const float*)d_in[8];
  const float* dh_w  = (const float*)d_in[9];
  const float* dx_w  = (const float*)d_in[10];
  const float* db_w  = (const float*)d_in[11];
  const float* db_b  = (const float*)d_in[12];
  const float* w_h   = (const float*)d_in[13];
  const float* w_x   = (const float*)d_in[14];
  const float* ln_w  = (const float*)d_in[15];
  const float* ln_b  = (const float*)d_in[16];

  char* ws = (char*)d_ws;
  unsigned short* h_bf    = (unsigned short*)(ws + 0);          //  4 MB
  unsigned short* x_bf    = (unsigned short*)(ws + 4194304);    //  4 MB (contig)
  unsigned short* meta_bf = (unsigned short*)(ws + 8388608);    //  1 MB
  unsigned short* Wh      = (unsigned short*)(ws + 9437184);    //  8 MB
  unsigned short* Wx      = (unsigned short*)(ws + 17825792);   //  8 MB (contig)
  unsigned short* Wd      = (unsigned short*)(ws + 26214400);   //  6 MB
  unsigned short* WzT     = (unsigned short*)(ws + 32505856);   //  1.5 MB
  unsigned short* E       = (unsigned short*)(ws + 34078720);   //  6 MB
  float*          F       = (float*)(ws + 40370176);            //  48 KB
  unsigned short* dall    = (unsigned short*)(ws + 40419328);   // 48 MB
  unsigned short* whx     = (unsigned short*)(ws + 90750976);   // 32 MB
  if (ws_size < 124305408) return;

  SegTable st;
  int i = 0, total = 0;
  auto add = [&](const float* s, unsigned short* d, int n) {
    st.src[i] = s; st.dst[i] = d; st.chunks[i] = n / 4096;
    total += n / 4096; ++i;
  };
  add(h_in, h_bf, 2048 * 1024);
  add(src_x, x_bf, 2048 * 1024);
  add(meta, meta_bf, 2048 * 256);
  add(w_h, Wh, 4096 * 1024);
  add(w_x, Wx, 4096 * 1024);
  add(dh_w, Wd, 4 * 1024 * 256);
  add(dx_w, Wd + 1048576, 4 * 1024 * 256);
  add(db_w, Wd + 2097152, 4 * 1024 * 256);

  // fused preprocessing: casts + z-weight transpose-cast + F bias
  prep_kernel<<<total + 192 + 132, 256, 0, stream>>>(
      st, total, zh_w, zx_w, zb_w, WzT, zh_b, zx_b, db_b, dh_w, dx_w, F);

  // E[zz] = Wd[zz] @ WzT[zz] (NT), 12 x (1024 x 256, K=256)
  gemm_e<<<dim3(2, 8, 12), 256, 0, stream>>>(Wd, WzT, E);

  // dall = meta @ E^T + F, 12 x (2048 x 1024, K=256)
  gemm_d<<<dim3(8, 16, 12), 256, 0, stream>>>(meta_bf, E, dall, F);

  // wh/wx via 256^2 kernel (grid exactly 256 blocks)
  gemm256_whx<<<256, 512, 0, stream>>>(h_bf, Wh, whx);

  // fused LN + gates
  epilogue_kernel<<<2048, 256, 0, stream>>>(dall, whx, c_in, ln_w, ln_b,
                                            (float*)d_out);
}

// Round 9
// 130.095 us; speedup vs baseline: 1.0565x; 1.0565x over previous
//
#include <hip/hip_runtime.h>

typedef __attribute__((ext_vector_type(4))) float f32x4;
typedef __attribute__((ext_vector_type(16))) float f32x16;
typedef __attribute__((ext_vector_type(8))) short bf16x8;

#define DEVFN static __device__ __forceinline__

DEVFN unsigned short f2bf(float f) {
  union { float f; unsigned u; } x; x.f = f;
  unsigned r = x.u + 0x7fffu + ((x.u >> 16) & 1u);
  return (unsigned short)(r >> 16);
}
DEVFN float bf2f(unsigned short u) {
  union { unsigned u; float f; } x; x.u = ((unsigned)u) << 16;
  return x.f;
}

DEVFN void gload_lds16(const unsigned short* g, unsigned short* l) {
  __builtin_amdgcn_global_load_lds(
      (const __attribute__((address_space(1))) unsigned int*)g,
      (__attribute__((address_space(3))) unsigned int*)l, 16, 0, 0);
}

// ---------------------------------------------------------------------------
// prep kernel: fused {fp32->bf16 casts} + {z-weight transpose-cast} + {F bias}
// ---------------------------------------------------------------------------
#define NSEG 8
struct SegTable {
  const float* src[NSEG];
  unsigned short* dst[NSEG];
  int chunks[NSEG];
};

__global__ __launch_bounds__(256) void prep_kernel(
    SegTable st, int castChunks,
    const float* __restrict__ zh_w, const float* __restrict__ zx_w,
    const float* __restrict__ zb_w, unsigned short* __restrict__ WzT,
    const float* __restrict__ zh_b, const float* __restrict__ zx_b,
    const float* __restrict__ db_b, const float* __restrict__ dh_w,
    const float* __restrict__ dx_w, float* __restrict__ F) {
  __shared__ float T[64][65];
  const int tid = threadIdx.x;
  int b = blockIdx.x;

  if (b < castChunks) {  // ---- segment casts ----
    int c = b, s = 0;
    while (c >= st.chunks[s]) { c -= st.chunks[s]; ++s; }
    const float* src = st.src[s] + (long)c * 4096;
    unsigned short* dst = st.dst[s] + (long)c * 4096;
#pragma unroll
    for (int i = 0; i < 4; ++i) {
      float4 v = *(const float4*)(src + tid * 4 + i * 1024);
      ushort4 o;
      o.x = f2bf(v.x); o.y = f2bf(v.y); o.z = f2bf(v.z); o.w = f2bf(v.w);
      *(ushort4*)(dst + tid * 4 + i * 1024) = o;
    }
    return;
  }
  b -= castChunks;

  if (b < 192) {  // ---- tcast_z: WzT[zz][k][j] = zw_t[g*256+j][k] ----
    const int zz = b >> 4, rem = b & 15;
    const int t = zz >> 2, g = zz & 3;
    const float* src =
        (t == 0 ? zh_w : (t == 1 ? zx_w : zb_w)) + (long)g * 65536;
    unsigned short* dst = WzT + (long)zz * 65536;
    const int j0 = (rem & 3) * 64, k0 = (rem >> 2) * 64;
    const int jr = tid >> 2, kc = (tid & 3) * 16;
#pragma unroll
    for (int i = 0; i < 4; ++i) {
      float4 v = *(const float4*)(src + (long)(j0 + jr) * 256 + k0 + kc + i * 4);
      T[jr][kc + i * 4 + 0] = v.x;
      T[jr][kc + i * 4 + 1] = v.y;
      T[jr][kc + i * 4 + 2] = v.z;
      T[jr][kc + i * 4 + 3] = v.w;
    }
    __syncthreads();
    const int kr = tid >> 2, jc = (tid & 3) * 16;
    unsigned short tmp[16];
#pragma unroll
    for (int i = 0; i < 16; ++i) tmp[i] = f2bf(T[jc + i][kr]);
    *(bf16x8*)(dst + (long)(k0 + kr) * 256 + j0 + jc) = *(bf16x8*)&tmp[0];
    *(bf16x8*)(dst + (long)(k0 + kr) * 256 + j0 + jc + 8) = *(bf16x8*)&tmp[8];
    return;
  }
  b -= 192;

  // ---- fbias: F[0/1][g][h] = sum_j zb[t][g*256+j]*dw_t[g][h][j]; F[2]=db_b
  if (b >= 128) {
    const int idx = (b - 128) * 1024 + tid * 4;
    *(float4*)(F + 8192 + idx) = *(const float4*)(db_b + idx);
    return;
  }
  const int wgid = b * 4 + (tid >> 6);  // 0..511
  const int lane = tid & 63;
  const int t = wgid >> 8, g = (wgid >> 6) & 3, hbase = (wgid & 63) * 16;
  const float* zb = (t == 0 ? zh_b : zx_b) + g * 256;
  const float* dw = (t == 0 ? dh_w : dx_w) + (long)g * 262144;
  float4 zv = *(const float4*)(zb + lane * 4);
#pragma unroll
  for (int i = 0; i < 16; ++i) {
    const int h = hbase + i;
    float4 wv = *(const float4*)(dw + (long)h * 256 + lane * 4);
    float s = zv.x * wv.x + zv.y * wv.y + zv.z * wv.z + zv.w * wv.w;
#pragma unroll
    for (int off = 32; off; off >>= 1) s += __shfl_down(s, off);
    if (lane == 0) F[(t * 4 + g) * 1024 + h] = s;
  }
}

// ---------------------------------------------------------------------------
// 128x128 NT bf16 GEMM body (m97 structure, round-4/6 proven layout).
// ---------------------------------------------------------------------------
DEVFN void gemm128_body(const unsigned short* __restrict__ A,
                        const unsigned short* __restrict__ W,
                        unsigned short* __restrict__ C,
                        const float* __restrict__ bias,
                        int lda, int ldb, int ldc, int K,
                        int bx, int by,
                        unsigned short* As, unsigned short* Bs) {
  const int m0 = by * 128, n0 = bx * 128;
  const int tid = threadIdx.x;
  const int lane = tid & 63, wid = tid >> 6;
  const int wr = wid >> 1, wc = wid & 1;

  const int srow = tid >> 2, scol = (tid & 3) * 8;
  const unsigned short* Ag0 = A + (long)(m0 + srow) * lda + scol;
  const unsigned short* Ag1 = A + (long)(m0 + 64 + srow) * lda + scol;
  const unsigned short* Wg0 = W + (long)(n0 + srow) * ldb + scol;
  const unsigned short* Wg1 = W + (long)(n0 + 64 + srow) * ldb + scol;
  unsigned short* As0 = &As[tid * 8];
  unsigned short* As1 = &As[2048 + tid * 8];
  unsigned short* Bs0 = &Bs[tid * 8];
  unsigned short* Bs1 = &Bs[2048 + tid * 8];

  const int r = lane & 15, q = lane >> 4;

  f32x4 acc[4][4];
#pragma unroll
  for (int m = 0; m < 4; ++m)
#pragma unroll
    for (int n = 0; n < 4; ++n) acc[m][n] = (f32x4)0.f;

  for (int k0 = 0; k0 < K; k0 += 32) {
    gload_lds16(Ag0 + k0, As0);
    gload_lds16(Ag1 + k0, As1);
    gload_lds16(Wg0 + k0, Bs0);
    gload_lds16(Wg1 + k0, Bs1);
    __syncthreads();

    bf16x8 af[4], bfr[4];
#pragma unroll
    for (int m = 0; m < 4; ++m)
      af[m] = *(const bf16x8*)&As[(wr * 64 + m * 16 + r) * 32 + q * 8];
#pragma unroll
    for (int n = 0; n < 4; ++n)
      bfr[n] = *(const bf16x8*)&Bs[(wc * 64 + n * 16 + r) * 32 + q * 8];
#pragma unroll
    for (int m = 0; m < 4; ++m)
#pragma unroll
      for (int n = 0; n < 4; ++n)
        acc[m][n] = __builtin_amdgcn_mfma_f32_16x16x32_bf16(af[m], bfr[n],
                                                            acc[m][n], 0, 0, 0);
    __syncthreads();
  }

#pragma unroll
  for (int m = 0; m < 4; ++m) {
    const int row = m0 + wr * 64 + m * 16 + q * 4;
#pragma unroll
    for (int n = 0; n < 4; ++n) {
      const int col = n0 + wc * 64 + n * 16 + r;
      float bv = bias ? bias[col] : 0.f;
#pragma unroll
      for (int j = 0; j < 4; ++j) {
        float v = acc[m][n][j] + bv;
        C[(long)(row + j) * ldc + col] = f2bf(v);
      }
    }
  }
}

// E-GEMM: E[zz] (1024h x 256k) = Wd[zz] @ WzT[zz] (NT)
__global__ __launch_bounds__(256) void gemm_e(
    const unsigned short* __restrict__ Wd, const unsigned short* __restrict__ WzT,
    unsigned short* __restrict__ E) {
  __shared__ __align__(16) unsigned short As[4096];
  __shared__ __align__(16) unsigned short Bs[4096];
  const int zz = blockIdx.z;
  gemm128_body(Wd + (long)zz * 262144, WzT + (long)zz * 65536,
               E + (long)zz * 262144, nullptr,
               256, 256, 256, 256, blockIdx.x, blockIdx.y, As, Bs);
}

// ---------------------------------------------------------------------------
// gemm_y: per block (bx, by, g): three K=256 GEMM passes (t = h, x, b) of
// meta @ E[t*4+g]^T; each pass bounces d = acc+F through LDS (fragment ->
// linear layout transpose), combines with COALESCED whx reads into linear
// fp32 yacc; final coalesced Y store.  S = 32KB (GEMM staging uses first 16KB).
// ---------------------------------------------------------------------------
__global__ __launch_bounds__(256) void gemm_y(
    const unsigned short* __restrict__ meta_bf,  // [2048][256]
    const unsigned short* __restrict__ E,        // [12][1024][256]
    const unsigned short* __restrict__ whx,      // [2][2048][4096]
    const float* __restrict__ F,                 // [12][1024]
    unsigned short* __restrict__ Y) {            // [2048][4096]
  __shared__ __align__(16) unsigned short S[16384];  // 32KB
  unsigned short* As = S;
  unsigned short* Bs = S + 4096;

  const int g = blockIdx.z;
  const int m0 = blockIdx.y * 128, n0 = blockIdx.x * 128;
  const int tid = threadIdx.x;
  const int lane = tid & 63, wid = tid >> 6;
  const int wr = wid >> 1, wc = wid & 1;
  const int r = lane & 15, q = lane >> 4;
  const int srow = tid >> 2, scol = (tid & 3) * 8;
  const int lrow = tid >> 4, lcol = (tid & 15) * 8;  // linear ownership

  const unsigned short* Ag0 = meta_bf + (long)(m0 + srow) * 256 + scol;
  const unsigned short* Ag1 = meta_bf + (long)(m0 + 64 + srow) * 256 + scol;
  unsigned short* As0 = &As[tid * 8];
  unsigned short* As1 = &As[2048 + tid * 8];
  unsigned short* Bs0 = &Bs[tid * 8];
  unsigned short* Bs1 = &Bs[2048 + tid * 8];

  float yacc[8][8];
#pragma unroll
  for (int i = 0; i < 8; ++i)
#pragma unroll
    for (int e = 0; e < 8; ++e) yacc[i][e] = 0.f;

#pragma unroll 1
  for (int t = 0; t < 3; ++t) {
    const int zz = t * 4 + g;
    const unsigned short* W = E + (long)zz * 262144;
    const unsigned short* Wg0 = W + (long)(n0 + srow) * 256 + scol;
    const unsigned short* Wg1 = W + (long)(n0 + 64 + srow) * 256 + scol;

    f32x4 acc[4][4];
#pragma unroll
    for (int m = 0; m < 4; ++m)
#pragma unroll
      for (int n = 0; n < 4; ++n) acc[m][n] = (f32x4)0.f;

    for (int k0 = 0; k0 < 256; k0 += 32) {
      gload_lds16(Ag0 + k0, As0);
      gload_lds16(Ag1 + k0, As1);
      gload_lds16(Wg0 + k0, Bs0);
      gload_lds16(Wg1 + k0, Bs1);
      __syncthreads();

      bf16x8 af[4], bfr[4];
#pragma unroll
      for (int m = 0; m < 4; ++m)
        af[m] = *(const bf16x8*)&As[(wr * 64 + m * 16 + r) * 32 + q * 8];
#pragma unroll
      for (int n = 0; n < 4; ++n)
        bfr[n] = *(const bf16x8*)&Bs[(wc * 64 + n * 16 + r) * 32 + q * 8];
#pragma unroll
      for (int m = 0; m < 4; ++m)
#pragma unroll
        for (int n = 0; n < 4; ++n)
          acc[m][n] = __builtin_amdgcn_mfma_f32_16x16x32_bf16(
              af[m], bfr[n], acc[m][n], 0, 0, 0);
      __syncthreads();
    }

    // scatter d = acc + F into S (fragment layout -> [128][128] bf16 tile)
    const float* Fz = F + (long)zz * 1024 + n0;
#pragma unroll
    for (int n = 0; n < 4; ++n) {
      const int col = wc * 64 + n * 16 + r;
      const float fv = Fz[col];
#pragma unroll
      for (int m = 0; m < 4; ++m) {
        const int rowb = wr * 64 + m * 16 + q * 4;
#pragma unroll
        for (int j = 0; j < 4; ++j)
          S[(rowb + j) * 128 + col] = f2bf(acc[m][n][j] + fv);
      }
    }
    __syncthreads();

    // linear combine: dv from LDS (16B/lane), wv coalesced from global
    if (t < 2) {
      const unsigned short* wsrc =
          whx + (long)t * 8388608 + (long)m0 * 4096 + g * 1024 + n0;
#pragma unroll
      for (int i = 0; i < 8; ++i) {
        bf16x8 dv = *(const bf16x8*)&S[(i * 16 + lrow) * 128 + lcol];
        bf16x8 wv = *(const bf16x8*)(wsrc + (long)(i * 16 + lrow) * 4096 + lcol);
#pragma unroll
        for (int e = 0; e < 8; ++e)
          yacc[i][e] += bf2f((unsigned short)dv[e]) * bf2f((unsigned short)wv[e]);
      }
    } else {
#pragma unroll
      for (int i = 0; i < 8; ++i) {
        bf16x8 dv = *(const bf16x8*)&S[(i * 16 + lrow) * 128 + lcol];
#pragma unroll
        for (int e = 0; e < 8; ++e)
          yacc[i][e] += bf2f((unsigned short)dv[e]);
      }
    }
    __syncthreads();  // S free for next pass staging
  }

  // coalesced Y store
  unsigned short* Yt = Y + (long)m0 * 4096 + g * 1024 + n0;
#pragma unroll
  for (int i = 0; i < 8; ++i) {
    unsigned short tmp[8];
#pragma unroll
    for (int e = 0; e < 8; ++e) tmp[e] = f2bf(yacc[i][e]);
    *(bf16x8*)(Yt + (long)(i * 16 + lrow) * 4096 + lcol) = *(bf16x8*)&tmp[0];
  }
}

// ---------------------------------------------------------------------------
// 256x256 / BK=64 / 8-wave / 32x32x16 bf16 GEMM (round-4/6 proven, verbatim).
// ---------------------------------------------------------------------------
__global__ __launch_bounds__(512, 2) void gemm256_whx(
    const unsigned short* __restrict__ Aall,   // [2][2048][1024]
    const unsigned short* __restrict__ Ball,   // [2][4096][1024]
    unsigned short* __restrict__ Call) {       // [2][2048][4096]
  __shared__ __align__(16) unsigned short As[2][2][8192];  // [buf][half][128*64]
  __shared__ __align__(16) unsigned short Bs[2][2][8192];

  const int bid = blockIdx.x;
  const int swz = (bid & 7) * 32 + (bid >> 3);
  const int z = swz >> 7;
  const int rr = swz & 127;
  const int sb = rr >> 5, wq = rr & 31;
  const int my = (sb & 1) * 4 + (wq >> 3);   // 0..7
  const int nx = (sb >> 1) * 8 + (wq & 7);   // 0..15

  const unsigned short* Ag = Aall + (long)z * 2097152 + (long)my * 262144;
  const unsigned short* Bg = Ball + (long)z * 4194304 + (long)nx * 262144;
  unsigned short* Cg = Call + (long)z * 8388608 + (long)my * 1048576 + nx * 256;

  const int tid = threadIdx.x;
  const int lane = tid & 63, wid = tid >> 6;
  const int wm = wid >> 2, wn = wid & 3;       // 2 x 4 wave grid
  const int l31 = lane & 31, l5 = lane >> 5;
  const int sw = l31 & 7;

  const int srow = tid >> 3, sslot = tid & 7;
  const int gcol = (sslot ^ (srow & 7)) * 8;
  const unsigned short* AgS = Ag + (long)srow * 1024 + gcol;
  const unsigned short* BgS = Bg + (long)srow * 1024 + gcol;

  auto stageA = [&](int buf, int half, int kt) {
    const unsigned short* s = AgS + half * 131072 + kt * 64;
    unsigned short* d = &As[buf][half][tid * 8];
    gload_lds16(s, d);
    gload_lds16(s + 65536, d + 4096);
  };
  auto stageB = [&](int buf, int half, int kt) {
    const unsigned short* s = BgS + half * 131072 + kt * 64;
    unsigned short* d = &Bs[buf][half][tid * 8];
    gload_lds16(s, d);
    gload_lds16(s + 65536, d + 4096);
  };

  int koff[4];
#pragma unroll
  for (int ks = 0; ks < 4; ++ks) koff[ks] = ((ks * 2 + l5) ^ sw) * 8;

  const int bhalf = wn >> 1;
  int brow[2];
#pragma unroll
  for (int nt = 0; nt < 2; ++nt) brow[nt] = ((wn & 1) * 64 + nt * 32 + l31) * 64;
  int arow[4];
#pragma unroll
  for (int mt = 0; mt < 4; ++mt) arow[mt] = (mt * 32 + l31) * 64;

  f32x16 acc[4][2];  // [mt][nt]
#pragma unroll
  for (int m = 0; m < 4; ++m)
#pragma unroll
    for (int n = 0; n < 2; ++n) acc[m][n] = (f32x16)0.f;

  stageA(0, 0, 0); stageB(0, 0, 0); stageA(0, 1, 0); stageB(0, 1, 0);
  stageA(1, 0, 1); stageB(1, 0, 1);
  asm volatile("s_waitcnt vmcnt(4)" ::: "memory");  // tile0 landed
  __builtin_amdgcn_s_barrier();

#pragma unroll 2
  for (int T = 0; T < 16; ++T) {
    const int buf = T & 1, nb = buf ^ 1;

    if (T < 15) { stageA(nb, 1, T + 1); stageB(nb, 1, T + 1); }

    bf16x8 bfg[2][4], af[2][4];
    const unsigned short* Ab = &As[buf][wm][0];
    {
      const unsigned short* Bb = &Bs[buf][bhalf][0];
#pragma unroll
      for (int nt = 0; nt < 2; ++nt)
#pragma unroll
        for (int ks = 0; ks < 4; ++ks)
          bfg[nt][ks] = *(const bf16x8*)(Bb + brow[nt] + koff[ks]);
#pragma unroll
      for (int m2 = 0; m2 < 2; ++m2)
#pragma unroll
        for (int ks = 0; ks < 4; ++ks)
          af[m2][ks] = *(const bf16x8*)(Ab + arow[m2] + koff[ks]);
    }

    __builtin_amdgcn_s_setprio(1);
#pragma unroll
    for (int m2 = 0; m2 < 2; ++m2)
#pragma unroll
      for (int nt = 0; nt < 2; ++nt)
#pragma unroll
        for (int ks = 0; ks < 4; ++ks)
          acc[m2][nt] = __builtin_amdgcn_mfma_f32_32x32x16_bf16(
              af[m2][ks], bfg[nt][ks], acc[m2][nt], 0, 0, 0);
    __builtin_amdgcn_s_setprio(0);

#pragma unroll
    for (int m2 = 0; m2 < 2; ++m2)
#pragma unroll
      for (int ks = 0; ks < 4; ++ks)
        af[m2][ks] = *(const bf16x8*)(Ab + arow[2 + m2] + koff[ks]);

    asm volatile("s_waitcnt lgkmcnt(0)" ::: "memory");
    __builtin_amdgcn_sched_barrier(0);
    __builtin_amdgcn_s_barrier();

    if (T < 14) { stageA(buf, 0, T + 2); stageB(buf, 0, T + 2); }

    __builtin_amdgcn_s_setprio(1);
#pragma unroll
    for (int m2 = 0; m2 < 2; ++m2)
#pragma unroll
      for (int nt = 0; nt < 2; ++nt)
#pragma unroll
        for (int ks = 0; ks < 4; ++ks)
          acc[2 + m2][nt] = __builtin_amdgcn_mfma_f32_32x32x16_bf16(
              af[m2][ks], bfg[nt][ks], acc[2 + m2][nt], 0, 0, 0);
    __builtin_amdgcn_s_setprio(0);

    if (T < 14) {
      asm volatile("s_waitcnt vmcnt(4)" ::: "memory");
      __builtin_amdgcn_s_barrier();
    } else if (T == 14) {
      asm volatile("s_waitcnt vmcnt(0)" ::: "memory");
      __builtin_amdgcn_s_barrier();
    }
  }

  // epilogue: 32x32 C/D layout: col = lane&31, row = (reg&3)+8*(reg>>2)+4*l5
#pragma unroll
  for (int mt = 0; mt < 4; ++mt) {
#pragma unroll
    for (int nt = 0; nt < 2; ++nt) {
      const int rb = wm * 128 + mt * 32 + 4 * l5;
      const int cb = wn * 64 + nt * 32 + l31;
#pragma unroll
      for (int reg = 0; reg < 16; ++reg) {
        const int row = rb + (reg & 3) + 8 * (reg >> 2);
        Cg[(long)row * 4096 + cb] = f2bf(acc[mt][nt][reg]);
      }
    }
  }
}

// ---------------------------------------------------------------------------
// Slim epilogue: read y, per-(b,g) LayerNorm, LSTM gates.
// ---------------------------------------------------------------------------
DEVFN void ld4bf(const unsigned short* p, float* o) {
  ushort4 v = *(const ushort4*)p;
  o[0] = bf2f(v.x); o[1] = bf2f(v.y); o[2] = bf2f(v.z); o[3] = bf2f(v.w);
}

__global__ __launch_bounds__(256) void epilogue2(
    const unsigned short* __restrict__ Y,       // [2048][4096] bf16
    const float* __restrict__ c_in,             // [2048][1024]
    const float* __restrict__ ln_w, const float* __restrict__ ln_b,
    float* __restrict__ out) {
  const long b = blockIdx.x;
  const int t = threadIdx.x;
  const int lane = t & 63, wid = t >> 6;

  __shared__ float redS[4][4], redQ[4][4];
  float y[4][4];

#pragma unroll
  for (int g = 0; g < 4; ++g) {
    ld4bf(Y + b * 4096 + g * 1024 + t * 4, y[g]);
    float s = 0.f, sq = 0.f;
#pragma unroll
    for (int j = 0; j < 4; ++j) { s += y[g][j]; sq += y[g][j] * y[g][j]; }
#pragma unroll
    for (int off = 32; off; off >>= 1) {
      s += __shfl_down(s, off);
      sq += __shfl_down(sq, off);
    }
    if (lane == 0) { redS[g][wid] = s; redQ[g][wid] = sq; }
  }
  __syncthreads();

  float yn[4][4];
#pragma unroll
  for (int g = 0; g < 4; ++g) {
    float S = redS[g][0] + redS[g][1] + redS[g][2] + redS[g][3];
    float SQ = redQ[g][0] + redQ[g][1] + redQ[g][2] + redQ[g][3];
    float mu = S * (1.f / 1024.f);
    float var = SQ * (1.f / 1024.f) - mu * mu;
    float rs = rsqrtf(var + 1e-5f);
    const int base = g * 1024 + t * 4;
    float4 lw = *(const float4*)(ln_w + base);
    float4 lb = *(const float4*)(ln_b + base);
    yn[g][0] = (y[g][0] - mu) * rs * lw.x + lb.x;
    yn[g][1] = (y[g][1] - mu) * rs * lw.y + lb.y;
    yn[g][2] = (y[g][2] - mu) * rs * lw.z + lb.z;
    yn[g][3] = (y[g][3] - mu) * rs * lw.w + lb.w;
  }

  float4 cp = *(const float4*)(c_in + b * 1024 + t * 4);
  float cin[4] = {cp.x, cp.y, cp.z, cp.w};
  float hn[4], cn[4];
#pragma unroll
  for (int j = 0; j < 4; ++j) {
    float ii = yn[0][j], ff = yn[1][j], gg = yn[2][j], oo = yn[3][j];
    float si = 1.f / (1.f + expf(-ii));
    float sf = 1.f / (1.f + expf(-ff));
    float so = 1.f / (1.f + expf(-oo));
    float cnj = sf * cin[j] + si * tanhf(gg);
    cn[j] = cnj;
    hn[j] = so * tanhf(cnj);
  }
  float4 ho = {hn[0], hn[1], hn[2], hn[3]};
  float4 co = {cn[0], cn[1], cn[2], cn[3]};
  *(float4*)(out + b * 1024 + t * 4) = ho;
  *(float4*)(out + 2097152L + b * 1024 + t * 4) = co;
}

// ---------------------------------------------------------------------------
extern "C" void kernel_launch(void* const* d_in, const int* in_sizes, int n_in,
                              void* d_out, int out_size, void* d_ws,
                              size_t ws_size, hipStream_t stream) {
  const float* src_x = (const float*)d_in[0];
  const float* h_in  = (const float*)d_in[1];
  const float* c_in  = (const float*)d_in[2];
  const float* meta  = (const float*)d_in[3];
  const float* zh_w  = (const float*)d_in[4];
  const float* zh_b  = (const float*)d_in[5];
  const float* zx_w  = (const float*)d_in[6];
  const float* zx_b  = (const float*)d_in[7];
  const float* zb_w  = (const float*)d_in[8];
  const float* dh_w  = (const float*)d_in[9];
  const float* dx_w  = (const float*)d_in[10];
  const float* db_w  = (const float*)d_in[11];
  const float* db_b  = (const float*)d_in[12];
  const float* w_h   = (const float*)d_in[13];
  const float* w_x   = (const float*)d_in[14];
  const float* ln_w  = (const float*)d_in[15];
  const float* ln_b  = (const float*)d_in[16];

  char* ws = (char*)d_ws;
  unsigned short* h_bf    = (unsigned short*)(ws + 0);          //  4 MB
  unsigned short* x_bf    = (unsigned short*)(ws + 4194304);    //  4 MB (contig)
  unsigned short* meta_bf = (unsigned short*)(ws + 8388608);    //  1 MB
  unsigned short* Wh      = (unsigned short*)(ws + 9437184);    //  8 MB
  unsigned short* Wx      = (unsigned short*)(ws + 17825792);   //  8 MB (contig)
  unsigned short* Wd      = (unsigned short*)(ws + 26214400);   //  6 MB
  unsigned short* WzT     = (unsigned short*)(ws + 32505856);   //  1.5 MB
  unsigned short* E       = (unsigned short*)(ws + 34078720);   //  6 MB
  float*          F       = (float*)(ws + 40370176);            //  48 KB
  unsigned short* Ybuf    = (unsigned short*)(ws + 40419328);   // 16 MB
  unsigned short* whx     = (unsigned short*)(ws + 57196544);   // 32 MB
  if (ws_size < 90750976) return;

  SegTable st;
  int i = 0, total = 0;
  auto add = [&](const float* s, unsigned short* d, int n) {
    st.src[i] = s; st.dst[i] = d; st.chunks[i] = n / 4096;
    total += n / 4096; ++i;
  };
  add(h_in, h_bf, 2048 * 1024);
  add(src_x, x_bf, 2048 * 1024);
  add(meta, meta_bf, 2048 * 256);
  add(w_h, Wh, 4096 * 1024);
  add(w_x, Wx, 4096 * 1024);
  add(dh_w, Wd, 4 * 1024 * 256);
  add(dx_w, Wd + 1048576, 4 * 1024 * 256);
  add(db_w, Wd + 2097152, 4 * 1024 * 256);

  // fused preprocessing: casts + z-weight transpose-cast + F bias
  prep_kernel<<<total + 192 + 132, 256, 0, stream>>>(
      st, total, zh_w, zx_w, zb_w, WzT, zh_b, zx_b, db_b, dh_w, dx_w, F);

  // E[zz] = Wd[zz] @ WzT[zz] (NT), 12 x (1024 x 256, K=256)
  gemm_e<<<dim3(2, 8, 12), 256, 0, stream>>>(Wd, WzT, E);

  // wh/wx via 256^2 kernel (must precede gemm_y)
  gemm256_whx<<<256, 512, 0, stream>>>(h_bf, Wh, whx);

  // fused d-GEMMs + combine (LDS layout-bounce): Y = d_h*wh + d_x*wx + d_b
  gemm_y<<<dim3(8, 16, 4), 256, 0, stream>>>(meta_bf, E, whx, F, Ybuf);

  // slim LN + gates
  epilogue2<<<2048, 256, 0, stream>>>(Ybuf, c_in, ln_w, ln_b, (float*)d_out);
}

// Round 10
// 114.785 us; speedup vs baseline: 1.1974x; 1.1334x over previous
//
#include <hip/hip_runtime.h>

typedef __attribute__((ext_vector_type(4))) float f32x4;
typedef __attribute__((ext_vector_type(8))) short bf16x8;

#define DEVFN static __device__ __forceinline__

DEVFN unsigned short f2bf(float f) {
  union { float f; unsigned u; } x; x.f = f;
  unsigned r = x.u + 0x7fffu + ((x.u >> 16) & 1u);
  return (unsigned short)(r >> 16);
}
DEVFN float bf2f(unsigned short u) {
  union { unsigned u; float f; } x; x.u = ((unsigned)u) << 16;
  return x.f;
}

DEVFN void gload_lds16(const unsigned short* g, unsigned short* l) {
  __builtin_amdgcn_global_load_lds(
      (const __attribute__((address_space(1))) unsigned int*)g,
      (__attribute__((address_space(3))) unsigned int*)l, 16, 0, 0);
}

// ---------------------------------------------------------------------------
// prep kernel: fused {fp32->bf16 casts} + {z-weight transpose-cast} + {F bias}
// ---------------------------------------------------------------------------
#define NSEG 8
struct SegTable {
  const float* src[NSEG];
  unsigned short* dst[NSEG];
  int chunks[NSEG];
};

__global__ __launch_bounds__(256) void prep_kernel(
    SegTable st, int castChunks,
    const float* __restrict__ zh_w, const float* __restrict__ zx_w,
    const float* __restrict__ zb_w, unsigned short* __restrict__ WzT,
    const float* __restrict__ zh_b, const float* __restrict__ zx_b,
    const float* __restrict__ db_b, const float* __restrict__ dh_w,
    const float* __restrict__ dx_w, float* __restrict__ F) {
  __shared__ float T[64][65];
  const int tid = threadIdx.x;
  int b = blockIdx.x;

  if (b < castChunks) {  // ---- segment casts ----
    int c = b, s = 0;
    while (c >= st.chunks[s]) { c -= st.chunks[s]; ++s; }
    const float* src = st.src[s] + (long)c * 4096;
    unsigned short* dst = st.dst[s] + (long)c * 4096;
#pragma unroll
    for (int i = 0; i < 4; ++i) {
      float4 v = *(const float4*)(src + tid * 4 + i * 1024);
      ushort4 o;
      o.x = f2bf(v.x); o.y = f2bf(v.y); o.z = f2bf(v.z); o.w = f2bf(v.w);
      *(ushort4*)(dst + tid * 4 + i * 1024) = o;
    }
    return;
  }
  b -= castChunks;

  if (b < 192) {  // ---- tcast_z: WzT[zz][k][j] = zw_t[g*256+j][k] ----
    const int zz = b >> 4, rem = b & 15;
    const int t = zz >> 2, g = zz & 3;
    const float* src =
        (t == 0 ? zh_w : (t == 1 ? zx_w : zb_w)) + (long)g * 65536;
    unsigned short* dst = WzT + (long)zz * 65536;
    const int j0 = (rem & 3) * 64, k0 = (rem >> 2) * 64;
    const int jr = tid >> 2, kc = (tid & 3) * 16;
#pragma unroll
    for (int i = 0; i < 4; ++i) {
      float4 v = *(const float4*)(src + (long)(j0 + jr) * 256 + k0 + kc + i * 4);
      T[jr][kc + i * 4 + 0] = v.x;
      T[jr][kc + i * 4 + 1] = v.y;
      T[jr][kc + i * 4 + 2] = v.z;
      T[jr][kc + i * 4 + 3] = v.w;
    }
    __syncthreads();
    const int kr = tid >> 2, jc = (tid & 3) * 16;
    unsigned short tmp[16];
#pragma unroll
    for (int i = 0; i < 16; ++i) tmp[i] = f2bf(T[jc + i][kr]);
    *(bf16x8*)(dst + (long)(k0 + kr) * 256 + j0 + jc) = *(bf16x8*)&tmp[0];
    *(bf16x8*)(dst + (long)(k0 + kr) * 256 + j0 + jc + 8) = *(bf16x8*)&tmp[8];
    return;
  }
  b -= 192;

  // ---- fbias: F[0/1][g][h] = sum_j zb[t][g*256+j]*dw_t[g][h][j]; F[2]=db_b
  if (b >= 128) {
    const int idx = (b - 128) * 1024 + tid * 4;
    *(float4*)(F + 8192 + idx) = *(const float4*)(db_b + idx);
    return;
  }
  const int wgid = b * 4 + (tid >> 6);  // 0..511
  const int lane = tid & 63;
  const int t = wgid >> 8, g = (wgid >> 6) & 3, hbase = (wgid & 63) * 16;
  const float* zb = (t == 0 ? zh_b : zx_b) + g * 256;
  const float* dw = (t == 0 ? dh_w : dx_w) + (long)g * 262144;
  float4 zv = *(const float4*)(zb + lane * 4);
#pragma unroll
  for (int i = 0; i < 16; ++i) {
    const int h = hbase + i;
    float4 wv = *(const float4*)(dw + (long)h * 256 + lane * 4);
    float s = zv.x * wv.x + zv.y * wv.y + zv.z * wv.z + zv.w * wv.w;
#pragma unroll
    for (int off = 32; off; off >>= 1) s += __shfl_down(s, off);
    if (lane == 0) F[(t * 4 + g) * 1024 + h] = s;
  }
}

// ---------------------------------------------------------------------------
// 128x128 NT bf16 GEMM body (m97 structure, round-6 proven verbatim).
// ---------------------------------------------------------------------------
DEVFN void gemm128_body(const unsigned short* __restrict__ A,
                        const unsigned short* __restrict__ W,
                        unsigned short* __restrict__ C,
                        const float* __restrict__ bias,
                        int lda, int ldb, int ldc, int K,
                        int bx, int by,
                        unsigned short* As, unsigned short* Bs) {
  const int m0 = by * 128, n0 = bx * 128;
  const int tid = threadIdx.x;
  const int lane = tid & 63, wid = tid >> 6;
  const int wr = wid >> 1, wc = wid & 1;

  const int srow = tid >> 2, scol = (tid & 3) * 8;
  const unsigned short* Ag0 = A + (long)(m0 + srow) * lda + scol;
  const unsigned short* Ag1 = A + (long)(m0 + 64 + srow) * lda + scol;
  const unsigned short* Wg0 = W + (long)(n0 + srow) * ldb + scol;
  const unsigned short* Wg1 = W + (long)(n0 + 64 + srow) * ldb + scol;
  unsigned short* As0 = &As[tid * 8];
  unsigned short* As1 = &As[2048 + tid * 8];
  unsigned short* Bs0 = &Bs[tid * 8];
  unsigned short* Bs1 = &Bs[2048 + tid * 8];

  const int r = lane & 15, q = lane >> 4;

  f32x4 acc[4][4];
#pragma unroll
  for (int m = 0; m < 4; ++m)
#pragma unroll
    for (int n = 0; n < 4; ++n) acc[m][n] = (f32x4)0.f;

  for (int k0 = 0; k0 < K; k0 += 32) {
    gload_lds16(Ag0 + k0, As0);
    gload_lds16(Ag1 + k0, As1);
    gload_lds16(Wg0 + k0, Bs0);
    gload_lds16(Wg1 + k0, Bs1);
    __syncthreads();

    bf16x8 af[4], bfr[4];
#pragma unroll
    for (int m = 0; m < 4; ++m)
      af[m] = *(const bf16x8*)&As[(wr * 64 + m * 16 + r) * 32 + q * 8];
#pragma unroll
    for (int n = 0; n < 4; ++n)
      bfr[n] = *(const bf16x8*)&Bs[(wc * 64 + n * 16 + r) * 32 + q * 8];
#pragma unroll
    for (int m = 0; m < 4; ++m)
#pragma unroll
      for (int n = 0; n < 4; ++n)
        acc[m][n] = __builtin_amdgcn_mfma_f32_16x16x32_bf16(af[m], bfr[n],
                                                            acc[m][n], 0, 0, 0);
    __syncthreads();
  }

#pragma unroll
  for (int m = 0; m < 4; ++m) {
    const int row = m0 + wr * 64 + m * 16 + q * 4;
#pragma unroll
    for (int n = 0; n < 4; ++n) {
      const int col = n0 + wc * 64 + n * 16 + r;
      float bv = bias ? bias[col] : 0.f;
#pragma unroll
      for (int j = 0; j < 4; ++j) {
        float v = acc[m][n][j] + bv;
        C[(long)(row + j) * ldc + col] = f2bf(v);
      }
    }
  }
}

// E-GEMM: E[zz] (1024h x 256k) = Wd[zz] @ WzT[zz] (NT)
__global__ __launch_bounds__(256) void gemm_e(
    const unsigned short* __restrict__ Wd, const unsigned short* __restrict__ WzT,
    unsigned short* __restrict__ E) {
  __shared__ __align__(16) unsigned short As[4096];
  __shared__ __align__(16) unsigned short Bs[4096];
  const int zz = blockIdx.z;
  gemm128_body(Wd + (long)zz * 262144, WzT + (long)zz * 65536,
               E + (long)zz * 262144, nullptr,
               256, 256, 256, 256, blockIdx.x, blockIdx.y, As, Bs);
}

// d-GEMMs: dall[t][:, g*1024..] = meta @ E[zz]^T-form + F[zz]
__global__ __launch_bounds__(256) void gemm_d(
    const unsigned short* __restrict__ meta_bf, const unsigned short* __restrict__ E,
    unsigned short* __restrict__ dall, const float* __restrict__ F) {
  __shared__ __align__(16) unsigned short As[4096];
  __shared__ __align__(16) unsigned short Bs[4096];
  const int zz = blockIdx.z;
  unsigned short* C = dall + (long)(zz >> 2) * 8388608 + (zz & 3) * 1024;
  gemm128_body(meta_bf, E + (long)zz * 262144, C, F + zz * 1024,
               256, 256, 4096, 256, blockIdx.x, blockIdx.y, As, Bs);
}

// ---------------------------------------------------------------------------
// whx: 256x256 / BK=64 / 8-wave, m201-style 8-phase schedule with 16x16x32
// MFMA and round-2-verified fragment addressing.
//   Per tile T (4 phases, quadrants (mh,nh)=(0,0),(0,1),(1,0),(1,1)):
//   q1: read A-half0(8 ds) + B-half0(4 ds); stage A1(T+1)->nb
//   q2: read B-half1(4 ds);                 stage A0(T+2)->buf
//   q3: read A-half1(8 ds);                 stage B0(T+2)->buf
//   q4: (regs only);                        stage B1(T+2)->buf; vmcnt(6)
//   each phase: [ds][stage][barrier][lgkmcnt0][sched_barrier][prio1]
//               [16 MFMA][prio0][(q4: vmcnt)][barrier]
//   Overwrite windows (reads end): A0@q1, B0@q1, B1@q2, A1@q3 -> all safe.
//   vmcnt(6) FIFO ledger: retires A1(T+1) => tile T+1 fully in LDS.
//   Prologue: 7 half-tiles {tile0: A0,A1,B0,B1; tile1: A0,B0,B1}, vmcnt(6).
// ---------------------------------------------------------------------------
__global__ __launch_bounds__(512, 2) void gemm256_whx(
    const unsigned short* __restrict__ Aall,   // [2][2048][1024]
    const unsigned short* __restrict__ Ball,   // [2][4096][1024]
    unsigned short* __restrict__ Call) {       // [2][2048][4096]
  __shared__ __align__(16) unsigned short As[2][2][8192];  // [buf][half][128*64]
  __shared__ __align__(16) unsigned short Bs[2][2][8192];

  const int bid = blockIdx.x;
  const int swz = (bid & 7) * 32 + (bid >> 3);
  const int z = swz >> 7;
  const int rr = swz & 127;
  const int sb = rr >> 5, wq = rr & 31;
  const int my = (sb & 1) * 4 + (wq >> 3);   // 0..7
  const int nx = (sb >> 1) * 8 + (wq & 7);   // 0..15

  const unsigned short* Ag = Aall + (long)z * 2097152 + (long)my * 262144;
  const unsigned short* Bg = Ball + (long)z * 4194304 + (long)nx * 262144;
  unsigned short* Cg = Call + (long)z * 8388608 + (long)my * 1048576 + nx * 256;

  const int tid = threadIdx.x;
  const int lane = tid & 63, wid = tid >> 6;
  const int wm = wid >> 2, wn = wid & 3;       // 2 x 4 wave grid
  const int fr = lane & 15, fq = lane >> 4;
  const int s0 = fq ^ (fr & 7);

  // staging geometry (round-2/4 proven): slot s of row r holds glob slot s^(r&7)
  const int srow = tid >> 3, sslot = tid & 7;
  const int gcol = (sslot ^ (srow & 7)) * 8;
  const unsigned short* AgS = Ag + (long)srow * 1024 + gcol;
  const unsigned short* BgS = Bg + (long)srow * 1024 + gcol;

  auto stageA = [&](int buf, int half, int kt) {
    const unsigned short* s = AgS + half * 131072 + kt * 64;
    unsigned short* d = &As[buf][half][tid * 8];
    gload_lds16(s, d);
    gload_lds16(s + 65536, d + 4096);
  };
  auto stageB = [&](int buf, int half, int kt) {
    const unsigned short* s = BgS + half * 131072 + kt * 64;
    unsigned short* d = &Bs[buf][half][tid * 8];
    gload_lds16(s, d);
    gload_lds16(s + 65536, d + 4096);
  };

  int aoff[4], boff[2];
#pragma unroll
  for (int mf = 0; mf < 4; ++mf)
    aoff[mf] = (wm * 64 + mf * 16 + fr) * 64 + s0 * 8;
#pragma unroll
  for (int nf = 0; nf < 2; ++nf)
    boff[nf] = (wn * 32 + nf * 16 + fr) * 64 + s0 * 8;

  f32x4 acc[2][2][4][2];
#pragma unroll
  for (int i = 0; i < 2; ++i)
#pragma unroll
    for (int j = 0; j < 2; ++j)
#pragma unroll
      for (int m = 0; m < 4; ++m)
#pragma unroll
        for (int n = 0; n < 2; ++n) acc[i][j][m][n] = (f32x4)0.f;

  // prologue
  stageA(0, 0, 0); stageA(0, 1, 0); stageB(0, 0, 0); stageB(0, 1, 0);
  stageA(1, 0, 1); stageB(1, 0, 1); stageB(1, 1, 1);
  asm volatile("s_waitcnt vmcnt(6)" ::: "memory");  // tile0 landed
  __builtin_amdgcn_s_barrier();

  bf16x8 af[4][2], bA[2][2], bB[2][2];

#define PH_SYNC                                          \
  __builtin_amdgcn_s_barrier();                          \
  asm volatile("s_waitcnt lgkmcnt(0)" ::: "memory");     \
  __builtin_amdgcn_sched_barrier(0);

#define PH_MFMA(MH, NH, BR)                              \
  __builtin_amdgcn_s_setprio(1);                         \
  _Pragma("unroll")                                      \
  for (int mf = 0; mf < 4; ++mf)                         \
    _Pragma("unroll")                                    \
    for (int nf = 0; nf < 2; ++nf) {                     \
      acc[MH][NH][mf][nf] = __builtin_amdgcn_mfma_f32_16x16x32_bf16( \
          af[mf][0], BR[nf][0], acc[MH][NH][mf][nf], 0, 0, 0);       \
      acc[MH][NH][mf][nf] = __builtin_amdgcn_mfma_f32_16x16x32_bf16( \
          af[mf][1], BR[nf][1], acc[MH][NH][mf][nf], 0, 0, 0);       \
    }                                                    \
  __builtin_amdgcn_s_setprio(0);

#pragma unroll 2
  for (int T = 0; T < 16; ++T) {
    const int buf = T & 1, nb = buf ^ 1;

    {  // q1: (0,0) — read A-half0 + B-half0; stage A1(T+1)
      const unsigned short* Ab = &As[buf][0][0];
      const unsigned short* Bb = &Bs[buf][0][0];
#pragma unroll
      for (int mf = 0; mf < 4; ++mf) {
        af[mf][0] = *(const bf16x8*)(Ab + aoff[mf]);
        af[mf][1] = *(const bf16x8*)(Ab + (aoff[mf] ^ 32));
      }
#pragma unroll
      for (int nf = 0; nf < 2; ++nf) {
        bA[nf][0] = *(const bf16x8*)(Bb + boff[nf]);
        bA[nf][1] = *(const bf16x8*)(Bb + (boff[nf] ^ 32));
      }
      if (T < 15) stageA(nb, 1, T + 1);
      PH_SYNC;
      PH_MFMA(0, 0, bA);
      __builtin_amdgcn_s_barrier();
    }
    {  // q2: (0,1) — read B-half1; stage A0(T+2)
      const unsigned short* Bb = &Bs[buf][1][0];
#pragma unroll
      for (int nf = 0; nf < 2; ++nf) {
        bB[nf][0] = *(const bf16x8*)(Bb + boff[nf]);
        bB[nf][1] = *(const bf16x8*)(Bb + (boff[nf] ^ 32));
      }
      if (T < 14) stageA(buf, 0, T + 2);
      PH_SYNC;
      PH_MFMA(0, 1, bB);
      __builtin_amdgcn_s_barrier();
    }
    {  // q3: (1,0) — read A-half1; stage B0(T+2)
      const unsigned short* Ab = &As[buf][1][0];
#pragma unroll
      for (int mf = 0; mf < 4; ++mf) {
        af[mf][0] = *(const bf16x8*)(Ab + aoff[mf]);
        af[mf][1] = *(const bf16x8*)(Ab + (aoff[mf] ^ 32));
      }
      if (T < 14) stageB(buf, 0, T + 2);
      PH_SYNC;
      PH_MFMA(1, 0, bA);
      __builtin_amdgcn_s_barrier();
    }
    {  // q4: (1,1) — regs only; stage B1(T+2); counted vmcnt
      if (T < 14) stageB(buf, 1, T + 2);
      PH_SYNC;
      PH_MFMA(1, 1, bB);
      if (T < 14) {
        asm volatile("s_waitcnt vmcnt(6)" ::: "memory");
      } else if (T == 14) {
        asm volatile("s_waitcnt vmcnt(0)" ::: "memory");
      }
      __builtin_amdgcn_s_barrier();
    }
  }
#undef PH_SYNC
#undef PH_MFMA

  // C store (round-2 verified layout)
#pragma unroll
  for (int mh = 0; mh < 2; ++mh)
#pragma unroll
    for (int nh = 0; nh < 2; ++nh)
#pragma unroll
      for (int mf = 0; mf < 4; ++mf)
#pragma unroll
        for (int nf = 0; nf < 2; ++nf) {
          const int row = mh * 128 + wm * 64 + mf * 16 + fq * 4;
          const int col = nh * 128 + wn * 32 + nf * 16 + fr;
#pragma unroll
          for (int j = 0; j < 4; ++j)
            Cg[(long)(row + j) * 4096 + col] = f2bf(acc[mh][nh][mf][nf][j]);
        }
}

// ---------------------------------------------------------------------------
// Epilogue: y = d_h*wh + d_x*wx + d_b ; per-(b,g) LayerNorm ; LSTM gates.
// ---------------------------------------------------------------------------
DEVFN void ld4bf(const unsigned short* p, float* o) {
  ushort4 v = *(const ushort4*)p;
  o[0] = bf2f(v.x); o[1] = bf2f(v.y); o[2] = bf2f(v.z); o[3] = bf2f(v.w);
}

__global__ __launch_bounds__(256) void epilogue_kernel(
    const unsigned short* __restrict__ d_all,   // [3][2048][4096] bf16
    const unsigned short* __restrict__ whx,     // [2][2048][4096] bf16
    const float* __restrict__ c_in,             // [2048][1024]
    const float* __restrict__ ln_w, const float* __restrict__ ln_b,
    float* __restrict__ out) {
  const long b = blockIdx.x;
  const int t = threadIdx.x;
  const int lane = t & 63, wid = t >> 6;

  const unsigned short* dh = d_all + b * 4096;
  const unsigned short* dx = d_all + 8388608L + b * 4096;
  const unsigned short* db = d_all + 16777216L + b * 4096;
  const unsigned short* wh = whx + b * 4096;
  const unsigned short* wx = whx + 8388608L + b * 4096;

  __shared__ float redS[4][4], redQ[4][4];
  float y[4][4];

#pragma unroll
  for (int g = 0; g < 4; ++g) {
    const int base = g * 1024 + t * 4;
    float fdh[4], fdx[4], fdb[4], fwh[4], fwx[4];
    ld4bf(dh + base, fdh);
    ld4bf(dx + base, fdx);
    ld4bf(db + base, fdb);
    ld4bf(wh + base, fwh);
    ld4bf(wx + base, fwx);
    float s = 0.f, sq = 0.f;
#pragma unroll
    for (int j = 0; j < 4; ++j) {
      float v = fdh[j] * fwh[j] + fdx[j] * fwx[j] + fdb[j];
      y[g][j] = v;
      s += v;
      sq += v * v;
    }
#pragma unroll
    for (int off = 32; off; off >>= 1) {
      s += __shfl_down(s, off);
      sq += __shfl_down(sq, off);
    }
    if (lane == 0) { redS[g][wid] = s; redQ[g][wid] = sq; }
  }
  __syncthreads();

  float yn[4][4];
#pragma unroll
  for (int g = 0; g < 4; ++g) {
    float S = redS[g][0] + redS[g][1] + redS[g][2] + redS[g][3];
    float SQ = redQ[g][0] + redQ[g][1] + redQ[g][2] + redQ[g][3];
    float mu = S * (1.f / 1024.f);
    float var = SQ * (1.f / 1024.f) - mu * mu;
    float rs = rsqrtf(var + 1e-5f);
    const int base = g * 1024 + t * 4;
    float4 lw = *(const float4*)(ln_w + base);
    float4 lb = *(const float4*)(ln_b + base);
    yn[g][0] = (y[g][0] - mu) * rs * lw.x + lb.x;
    yn[g][1] = (y[g][1] - mu) * rs * lw.y + lb.y;
    yn[g][2] = (y[g][2] - mu) * rs * lw.z + lb.z;
    yn[g][3] = (y[g][3] - mu) * rs * lw.w + lb.w;
  }

  float4 cp = *(const float4*)(c_in + b * 1024 + t * 4);
  float cin[4] = {cp.x, cp.y, cp.z, cp.w};
  float hn[4], cn[4];
#pragma unroll
  for (int j = 0; j < 4; ++j) {
    float ii = yn[0][j], ff = yn[1][j], gg = yn[2][j], oo = yn[3][j];
    float si = 1.f / (1.f + expf(-ii));
    float sf = 1.f / (1.f + expf(-ff));
    float so = 1.f / (1.f + expf(-oo));
    float cnj = sf * cin[j] + si * tanhf(gg);
    cn[j] = cnj;
    hn[j] = so * tanhf(cnj);
  }
  float4 ho = {hn[0], hn[1], hn[2], hn[3]};
  float4 co = {cn[0], cn[1], cn[2], cn[3]};
  *(float4*)(out + b * 1024 + t * 4) = ho;
  *(float4*)(out + 2097152L + b * 1024 + t * 4) = co;
}

// ---------------------------------------------------------------------------
extern "C" void kernel_launch(void* const* d_in, const int* in_sizes, int n_in,
                              void* d_out, int out_size, void* d_ws,
                              size_t ws_size, hipStream_t stream) {
  const float* src_x = (const float*)d_in[0];
  const float* h_in  = (const float*)d_in[1];
  const float* c_in  = (const float*)d_in[2];
  const float* meta  = (const float*)d_in[3];
  const float* zh_w  = (const float*)d_in[4];
  const float* zh_b  = (const float*)d_in[5];
  const float* zx_w  = (const float*)d_in[6];
  const float* zx_b  = (const float*)d_in[7];
  const float* zb_w  = (const float*)d_in[8];
  const float* dh_w  = (const float*)d_in[9];
  const float* dx_w  = (const float*)d_in[10];
  const float* db_w  = (const float*)d_in[11];
  const float* db_b  = (const float*)d_in[12];
  const float* w_h   = (const float*)d_in[13];
  const float* w_x   = (const float*)d_in[14];
  const float* ln_w  = (const float*)d_in[15];
  const float* ln_b  = (const float*)d_in[16];

  char* ws = (char*)d_ws;
  unsigned short* h_bf    = (unsigned short*)(ws + 0);          //  4 MB
  unsigned short* x_bf    = (unsigned short*)(ws + 4194304);    //  4 MB (contig)
  unsigned short* meta_bf = (unsigned short*)(ws + 8388608);    //  1 MB
  unsigned short* Wh      = (unsigned short*)(ws + 9437184);    //  8 MB
  unsigned short* Wx      = (unsigned short*)(ws + 17825792);   //  8 MB (contig)
  unsigned short* Wd      = (unsigned short*)(ws + 26214400);   //  6 MB
  unsigned short* WzT     = (unsigned short*)(ws + 32505856);   //  1.5 MB
  unsigned short* E       = (unsigned short*)(ws + 34078720);   //  6 MB
  float*          F       = (float*)(ws + 40370176);            //  48 KB
  unsigned short* dall    = (unsigned short*)(ws + 40419328);   // 48 MB
  unsigned short* whx     = (unsigned short*)(ws + 90750976);   // 32 MB
  if (ws_size < 124305408) return;

  SegTable st;
  int i = 0, total = 0;
  auto add = [&](const float* s, unsigned short* d, int n) {
    st.src[i] = s; st.dst[i] = d; st.chunks[i] = n / 4096;
    total += n / 4096; ++i;
  };
  add(h_in, h_bf, 2048 * 1024);
  add(src_x, x_bf, 2048 * 1024);
  add(meta, meta_bf, 2048 * 256);
  add(w_h, Wh, 4096 * 1024);
  add(w_x, Wx, 4096 * 1024);
  add(dh_w, Wd, 4 * 1024 * 256);
  add(dx_w, Wd + 1048576, 4 * 1024 * 256);
  add(db_w, Wd + 2097152, 4 * 1024 * 256);

  // fused preprocessing: casts + z-weight transpose-cast + F bias
  prep_kernel<<<total + 192 + 132, 256, 0, stream>>>(
      st, total, zh_w, zx_w, zb_w, WzT, zh_b, zx_b, db_b, dh_w, dx_w, F);

  // E[zz] = Wd[zz] @ WzT[zz] (NT), 12 x (1024 x 256, K=256)
  gemm_e<<<dim3(2, 8, 12), 256, 0, stream>>>(Wd, WzT, E);

  // dall = meta @ E^T + F, 12 x (2048 x 1024, K=256)
  gemm_d<<<dim3(8, 16, 12), 256, 0, stream>>>(meta_bf, E, dall, F);

  // wh/wx via 8-phase 256^2 kernel (grid exactly 256 blocks)
  gemm256_whx<<<256, 512, 0, stream>>>(h_bf, Wh, whx);

  // fused LN + gates
  epilogue_kernel<<<2048, 256, 0, stream>>>(dall, whx, c_in, ln_w, ln_b,
                                            (float*)d_out);
}